// Round 3
// baseline (1585.095 us; speedup 1.0000x reference)
//
#include <hip/hip_runtime.h>

typedef _Float16 half8 __attribute__((ext_vector_type(8)));
typedef float floatx16 __attribute__((ext_vector_type(16)));

#define TPB   256            // 4 waves
#define RPTS  512            // db points staged per round (per buffer)
#define NTILE (RPTS / 32)    // 16 tiles of 32 db points
#define SMH   (RPTS * 16)    // 8192 halfs = 16 KiB per buffer

// 32x32x16 f16 MFMA formulation. Each wave owns 64 queries (2 A-frags x 32 rows);
// block = 256 queries. db double-buffered in rounds of 512 points as pre-formatted
// B-fragments. Pipeline (2-deep, ONE barrier per round):
//   round r: issue first sweep ds_reads; ds_write regs(r+1) -> buf[cur^1];
//            issue loads(r+2) -> regs; sweep buf[cur] (UNROLLED, 1-ahead reg
//            prefetch, 4 MFMAs grouped before folds); __syncthreads().
// R2 lesson: VGPR=64 meant the compiler couldn't keep even 2 MFMA accumulators
// live -> fully serialized sweep (19% MfmaUtil, flat vs single-buffered). This
// version is structured for ~4 live accumulators within the 128-VGPR cap of
// __launch_bounds__(256,4).
// Staging data lives in SIX NAMED SCALARS (sx0..sz1) — never an array, never
// address-taken: round-1's pointer-lambda version demoted rm[] to scratch
// (3.8 GB scratch writes, 13x regression).
// K-slots (11 of 16 used):
//   B: (xh, xl, xh, yh, yl, yh, zh, zl | zh, hqh, hql, 0..)
//   A: (-xh,-xh,-xl,-yh,-yh,-yl,-zh,-zh | -zl, 1, 1, 0..)
// => acc = 0.5||q||^2 - p.q (split-f16, abs err ~5e-5);  dist = 2*(ph + min acc).
// A layout: row m = lane&31, k = (lane>>5)*8 + j.  B: col c = lane&31, same k.
// C/D: col = lane&31, row = (reg&3) + 8*(reg>>2) + 4*(lane>>5).

__device__ __forceinline__ void wr_point(_Float16* __restrict__ smb, int j,
                                         float x, float y, float z) {
    float hq = 0.5f * (x * x + y * y + z * z);
    _Float16 xh = (_Float16)x, yh = (_Float16)y, zh = (_Float16)z;
    _Float16 xl = (_Float16)(x - (float)xh);
    _Float16 yl = (_Float16)(y - (float)yh);
    _Float16 zl = (_Float16)(z - (float)zh);
    _Float16 qh = (_Float16)hq;
    _Float16 ql = (_Float16)(hq - (float)qh);
    const _Float16 hz = (_Float16)0.0f;
    int t = j >> 5, c = j & 31;
    half8 v0, v1;
    v0[0] = xh; v0[1] = xl; v0[2] = xh; v0[3] = yh;
    v0[4] = yl; v0[5] = yh; v0[6] = zh; v0[7] = zl;
    v1[0] = zh; v1[1] = qh; v1[2] = ql; v1[3] = hz;
    v1[4] = hz; v1[5] = hz; v1[6] = hz; v1[7] = hz;
    *(half8*)&smb[t * 512 + c * 8]       = v0;   // k-half 0
    *(half8*)&smb[t * 512 + 256 + c * 8] = v1;   // k-half 1
}

__global__ __launch_bounds__(TPB, 4) void chamfer_mfma(const float* __restrict__ xyz1,
                                                       const float* __restrict__ xyz2,
                                                       float* __restrict__ out,
                                                       int N, int M) {
    const int b = blockIdx.y, dir = blockIdx.z;
    const float* __restrict__ P = dir ? xyz2 + (size_t)b * M * 3 : xyz1 + (size_t)b * N * 3;
    const float* __restrict__ Q = dir ? xyz1 + (size_t)b * N * 3 : xyz2 + (size_t)b * M * 3;
    const int nq = dir ? M : N;
    const int md = dir ? N : M;

    if ((int)blockIdx.x * TPB >= nq) return;   // block-uniform, before any barrier

    __shared__ __align__(16) _Float16 smB[2][SMH];

    const int tid = (int)threadIdx.x;
    const int w   = tid >> 6;
    const int l   = tid & 63;
    const int m   = l & 31;      // A row / B col this lane serves
    const int h   = l >> 5;      // k-half: k = h*8 + j

    const _Float16 hz = (_Float16)0.0f, hone = (_Float16)1.0f;
    const int qb = blockIdx.x * 256 + w * 64;

    // ---- Build the wave's 2 A-fragments (held for the whole kernel) ----
    half8 afr[2];
#pragma unroll
    for (int g = 0; g < 2; ++g) {
        int idx = qb + g * 32 + m;
        int ci  = idx < nq ? idx : nq - 1;
        float x = P[3 * ci], y = P[3 * ci + 1], z = P[3 * ci + 2];
        _Float16 xh = (_Float16)x, yh = (_Float16)y, zh = (_Float16)z;
        _Float16 xl = (_Float16)(x - (float)xh);
        _Float16 yl = (_Float16)(y - (float)yh);
        _Float16 zl = (_Float16)(z - (float)zh);
        half8 a;
        if (h == 0) {
            a[0] = -xh; a[1] = -xh; a[2] = -xl; a[3] = -yh;
            a[4] = -yh; a[5] = -yl; a[6] = -zh; a[7] = -zh;
        } else {
            a[0] = -zl; a[1] = hone; a[2] = hone; a[3] = hz;
            a[4] = hz;  a[5] = hz;   a[6] = hz;  a[7] = hz;
        }
        afr[g] = a;
    }

    // ---- staging registers: named scalars ONLY (see header comment) ----
    float sx0, sy0, sz0, sx1, sy1, sz1;
#define LDPTS(rr) {                                                   \
        int g0 = (rr) * RPTS + tid;                                   \
        int g1 = g0 + TPB;                                            \
        g0 = g0 < md ? g0 : md - 1;  /* clamp-pad: dups never change a min */ \
        g1 = g1 < md ? g1 : md - 1;                                   \
        sx0 = Q[3 * g0]; sy0 = Q[3 * g0 + 1]; sz0 = Q[3 * g0 + 2];    \
        sx1 = Q[3 * g1]; sy1 = Q[3 * g1 + 1]; sz1 = Q[3 * g1 + 2];    \
    }
#define WRPTS(bb) {                                                   \
        wr_point(&smB[bb][0], tid,       sx0, sy0, sz0);              \
        wr_point(&smB[bb][0], tid + TPB, sx1, sy1, sz1);              \
    }

    float rm[32];
#pragma unroll
    for (int i = 0; i < 32; ++i) rm[i] = 3.0e38f;

    const floatx16 czero = {0.0f, 0.0f, 0.0f, 0.0f, 0.0f, 0.0f, 0.0f, 0.0f,
                            0.0f, 0.0f, 0.0f, 0.0f, 0.0f, 0.0f, 0.0f, 0.0f};
    const int nrounds = (md + RPTS - 1) / RPTS;

    // ---- prologue: buf0 <- round 0; regs <- round 1 ----
    LDPTS(0);
    WRPTS(0);
    if (nrounds > 1) LDPTS(1);
    __syncthreads();

    const _Float16* bp0 = &smB[0][h * 256 + m * 8];
    const _Float16* bp1 = &smB[1][h * 256 + m * 8];

    int cur = 0;
    for (int r = 0; r < nrounds; ++r) {
        const _Float16* bp = cur ? bp1 : bp0;

        // issue the first sweep reads before the staging write burst,
        // so 16 waves/CU of ds_writes overlap in-flight ds_reads
        half8 c0 = *(const half8*)(bp);
        half8 c1 = *(const half8*)(bp + 512);

        // write regs(r+1) -> other buffer (safe: barrier at end of r-1
        // cleared its readers); then issue loads for r+2.
        if (r + 1 < nrounds) {
            WRPTS(cur ^ 1);
            if (r + 2 < nrounds) LDPTS(r + 2);
        }

        // ---- Sweep buf[cur]: unrolled, 1-ahead register prefetch ----
#pragma unroll
        for (int t = 0; t < NTILE; t += 2) {
            half8 n0 = c0, n1 = c1;
            if (t + 2 < NTILE) {                    // compile-time branch
                n0 = *(const half8*)(bp + (t + 2) * 512);
                n1 = *(const half8*)(bp + (t + 3) * 512);
            }
            floatx16 d0a = __builtin_amdgcn_mfma_f32_32x32x16_f16(afr[0], c0, czero, 0, 0, 0);
            floatx16 d0b = __builtin_amdgcn_mfma_f32_32x32x16_f16(afr[0], c1, czero, 0, 0, 0);
            floatx16 d1a = __builtin_amdgcn_mfma_f32_32x32x16_f16(afr[1], c0, czero, 0, 0, 0);
            floatx16 d1b = __builtin_amdgcn_mfma_f32_32x32x16_f16(afr[1], c1, czero, 0, 0, 0);
#pragma unroll
            for (int i = 0; i < 16; ++i) {
                rm[i]      = fminf(fminf(rm[i],      d0a[i]), d0b[i]);   // -> v_min3
                rm[16 + i] = fminf(fminf(rm[16 + i], d1a[i]), d1b[i]);
            }
            c0 = n0; c1 = n1;
        }

        if (r + 1 < nrounds) __syncthreads();   // uniform; last round skips
        cur ^= 1;
    }

    // ---- Col-min across the 32 lanes of each k-half (rows identical per half) ----
#pragma unroll
    for (int off = 1; off < 32; off <<= 1) {
#pragma unroll
        for (int i = 0; i < 32; ++i) rm[i] = fminf(rm[i], __shfl_xor(rm[i], off, 64));
    }

    // ---- Emit: lanes c<16 of each half own one row each; recompute ph from P ----
    float s = 0.0f;
    if (m < 16) {
        const int reg = (m & 3) + 4 * (m >> 2);
        const int row = 4 * h + (m & 3) + 8 * (m >> 2);
#pragma unroll
        for (int g = 0; g < 2; ++g) {
            int idx = qb + g * 32 + row;
            if (idx < nq) {
                float x = P[3 * idx], y = P[3 * idx + 1], z = P[3 * idx + 2];
                s += rm[g * 16 + reg] + 0.5f * (x * x + y * y + z * z);
            }
        }
    }
#pragma unroll
    for (int off = 32; off > 0; off >>= 1) s += __shfl_down(s, off, 64);
    if (l == 0) atomicAdd(out + b, s * (2.0f / (float)nq));   // dist = 2*(ph+acc)
}

extern "C" void kernel_launch(void* const* d_in, const int* in_sizes, int n_in,
                              void* d_out, int out_size, void* d_ws, size_t ws_size,
                              hipStream_t stream) {
    const float* xyz1 = (const float*)d_in[0];
    const float* xyz2 = (const float*)d_in[1];
    float* out = (float*)d_out;

    const int B = out_size;
    const int N = in_sizes[0] / (3 * B);
    const int M = in_sizes[1] / (3 * B);

    hipMemsetAsync(d_out, 0, (size_t)B * sizeof(float), stream);

    const int qmax = N > M ? N : M;
    dim3 grid((qmax + 255) / 256, B, 2);
    chamfer_mfma<<<grid, dim3(TPB), 0, stream>>>(xyz1, xyz2, out, N, M);
}

// Round 4
// 676.676 us; speedup vs baseline: 2.3425x; 2.3425x over previous
//
#include <hip/hip_runtime.h>

typedef _Float16 half8 __attribute__((ext_vector_type(8)));
typedef float floatx16 __attribute__((ext_vector_type(16)));

#define TPB    256           // 4 waves
#define RPTS   256           // db points staged per round (= TPB: 1 pt/thread)
#define NTILE  (RPTS / 32)   // 8 tiles of 32 db points
#define SMH    (RPTS * 16)   // 4096 halfs = 8 KiB per buffer
#define NSPLIT 4             // md-split: blocks per (qblock, dir) pair

// 32x32x16 f16 MFMA formulation. Each wave owns 64 queries (2 A-frags x 32 rows);
// block = 256 queries x ONE md-chunk (md/NSPLIT db points). Partial per-query
// mins go to ws[chunk][dir][b][q] (4 MB); chamfer_reduce mins over chunks and
// mean-reduces. Rationale: total waves without md-split = 4096 = 16/CU = 4/SIMD
// (R0/R2: 28% occupancy, 19% MfmaUtil, latency-bound). NSPLIT=4 -> 4096 blocks,
// 8 resident/CU (16 KiB LDS each), 32 waves/CU, same total LDS/MFMA traffic.
// R3 lesson: do NOT unroll/group the sweep — 4 live floatx16 accs + rm[32]
// overflows the 64-VGPR budget (8 waves/SIMD) and spills rm to scratch
// (3.9 GB scratch traffic, 23x). R2's rolled sweep fits at exactly 64 VGPR.
// R1 lesson: staging data in named scalars only — never arrays/pointers.
// K-slots (11 of 16 used):
//   B: (xh, xl, xh, yh, yl, yh, zh, zl | zh, hqh, hql, 0..)
//   A: (-xh,-xh,-xl,-yh,-yh,-yl,-zh,-zh | -zl, 1, 1, 0..)
// => acc = 0.5||q||^2 - p.q (split-f16, abs err ~5e-5);  dist = 2*(ph + min acc).
// A layout: row m = lane&31, k = (lane>>5)*8 + j.  B: col c = lane&31, same k.
// C/D: col = lane&31, row = (reg&3) + 8*(reg>>2) + 4*(lane>>5).

__device__ __forceinline__ void wr_point(_Float16* __restrict__ smb, int j,
                                         float x, float y, float z) {
    float hq = 0.5f * (x * x + y * y + z * z);
    _Float16 xh = (_Float16)x, yh = (_Float16)y, zh = (_Float16)z;
    _Float16 xl = (_Float16)(x - (float)xh);
    _Float16 yl = (_Float16)(y - (float)yh);
    _Float16 zl = (_Float16)(z - (float)zh);
    _Float16 qh = (_Float16)hq;
    _Float16 ql = (_Float16)(hq - (float)qh);
    const _Float16 hz = (_Float16)0.0f;
    int t = j >> 5, c = j & 31;
    half8 v0, v1;
    v0[0] = xh; v0[1] = xl; v0[2] = xh; v0[3] = yh;
    v0[4] = yl; v0[5] = yh; v0[6] = zh; v0[7] = zl;
    v1[0] = zh; v1[1] = qh; v1[2] = ql; v1[3] = hz;
    v1[4] = hz; v1[5] = hz; v1[6] = hz; v1[7] = hz;
    *(half8*)&smb[t * 512 + c * 8]       = v0;   // k-half 0
    *(half8*)&smb[t * 512 + 256 + c * 8] = v1;   // k-half 1
}

__global__ __launch_bounds__(TPB, 8) void chamfer_mfma(const float* __restrict__ xyz1,
                                                       const float* __restrict__ xyz2,
                                                       float* __restrict__ ws,
                                                       int N, int M, int QCAP) {
    const int b = blockIdx.y, dir = blockIdx.z;
    const int B = gridDim.y;
    const int qblock = (int)blockIdx.x / NSPLIT;
    const int chunk  = (int)blockIdx.x % NSPLIT;
    const float* __restrict__ P = dir ? xyz2 + (size_t)b * M * 3 : xyz1 + (size_t)b * N * 3;
    const float* __restrict__ Q = dir ? xyz1 + (size_t)b * N * 3 : xyz2 + (size_t)b * M * 3;
    const int nq = dir ? M : N;
    const int md = dir ? N : M;

    if (qblock * 256 >= nq) return;   // block-uniform, before any barrier

    // chunk range: CH rounds up so NSPLIT*CH covers md; clamp-pad handles excess
    const int CH   = ((md + NSPLIT * RPTS - 1) / (NSPLIT * RPTS)) * RPTS;
    const int base = chunk * CH;
    const int nrounds = CH / RPTS;    // >= 1

    __shared__ __align__(16) _Float16 smB[2][SMH];

    const int tid = (int)threadIdx.x;
    const int w   = tid >> 6;
    const int l   = tid & 63;
    const int m   = l & 31;      // A row / B col this lane serves
    const int h   = l >> 5;      // k-half: k = h*8 + j

    const _Float16 hz = (_Float16)0.0f, hone = (_Float16)1.0f;
    const int qb = qblock * 256 + w * 64;

    // ---- Build the wave's 2 A-fragments (held for the whole kernel) ----
    half8 afr[2];
#pragma unroll
    for (int g = 0; g < 2; ++g) {
        int idx = qb + g * 32 + m;
        int ci  = idx < nq ? idx : nq - 1;
        float x = P[3 * ci], y = P[3 * ci + 1], z = P[3 * ci + 2];
        _Float16 xh = (_Float16)x, yh = (_Float16)y, zh = (_Float16)z;
        _Float16 xl = (_Float16)(x - (float)xh);
        _Float16 yl = (_Float16)(y - (float)yh);
        _Float16 zl = (_Float16)(z - (float)zh);
        half8 a;
        if (h == 0) {
            a[0] = -xh; a[1] = -xh; a[2] = -xl; a[3] = -yh;
            a[4] = -yh; a[5] = -yl; a[6] = -zh; a[7] = -zh;
        } else {
            a[0] = -zl; a[1] = hone; a[2] = hone; a[3] = hz;
            a[4] = hz;  a[5] = hz;   a[6] = hz;  a[7] = hz;
        }
        afr[g] = a;
    }

    // ---- staging registers: named scalars ONLY (R1 lesson) ----
    float sx0, sy0, sz0;
#define LDPTS(rr) {                                                   \
        int g0 = base + (rr) * RPTS + tid;                            \
        g0 = g0 < md ? g0 : md - 1;  /* clamp-pad: dups never change a min */ \
        sx0 = Q[3 * g0]; sy0 = Q[3 * g0 + 1]; sz0 = Q[3 * g0 + 2];    \
    }
#define WRPTS(bb) { wr_point(&smB[bb][0], tid, sx0, sy0, sz0); }

    float rm[32];
#pragma unroll
    for (int i = 0; i < 32; ++i) rm[i] = 3.0e38f;

    const floatx16 czero = {0.0f, 0.0f, 0.0f, 0.0f, 0.0f, 0.0f, 0.0f, 0.0f,
                            0.0f, 0.0f, 0.0f, 0.0f, 0.0f, 0.0f, 0.0f, 0.0f};

    // ---- prologue: buf0 <- round 0; regs <- round 1 ----
    LDPTS(0);
    WRPTS(0);
    if (nrounds > 1) LDPTS(1);
    __syncthreads();

    const _Float16* bp0 = &smB[0][h * 256 + m * 8];
    const _Float16* bp1 = &smB[1][h * 256 + m * 8];

    int cur = 0;
    for (int r = 0; r < nrounds; ++r) {
        // write regs(r+1) -> other buffer; then issue loads for r+2
        if (r + 1 < nrounds) {
            WRPTS(cur ^ 1);
            if (r + 2 < nrounds) LDPTS(r + 2);
        }

        // ---- Sweep buf[cur]: rolled (R2 form — fits 64 VGPR, no scratch) ----
        const _Float16* bp = cur ? bp1 : bp0;
        for (int t = 0; t < NTILE; t += 2) {
            half8 b0 = *(const half8*)(bp + t * 512);
            half8 b1 = *(const half8*)(bp + t * 512 + 512);
            floatx16 d0a = __builtin_amdgcn_mfma_f32_32x32x16_f16(afr[0], b0, czero, 0, 0, 0);
            floatx16 d0b = __builtin_amdgcn_mfma_f32_32x32x16_f16(afr[0], b1, czero, 0, 0, 0);
#pragma unroll
            for (int i = 0; i < 16; ++i)
                rm[i] = fminf(fminf(rm[i], d0a[i]), d0b[i]);         // -> v_min3
            floatx16 d1a = __builtin_amdgcn_mfma_f32_32x32x16_f16(afr[1], b0, czero, 0, 0, 0);
            floatx16 d1b = __builtin_amdgcn_mfma_f32_32x32x16_f16(afr[1], b1, czero, 0, 0, 0);
#pragma unroll
            for (int i = 0; i < 16; ++i)
                rm[16 + i] = fminf(fminf(rm[16 + i], d1a[i]), d1b[i]);
        }

        if (r + 1 < nrounds) __syncthreads();   // uniform; last round skips
        cur ^= 1;
    }

    // ---- Col-min across the 32 lanes of each k-half (rows identical per half) ----
#pragma unroll
    for (int off = 1; off < 32; off <<= 1) {
#pragma unroll
        for (int i = 0; i < 32; ++i) rm[i] = fminf(rm[i], __shfl_xor(rm[i], off, 64));
    }

    // ---- Emit partial mins to ws[chunk][dir][b][q] ----
    float* __restrict__ wsd = ws + (((size_t)chunk * 2 + dir) * B + b) * QCAP;
    if (m < 16) {
        const int reg = (m & 3) + 4 * (m >> 2);
        const int row = 4 * h + (m & 3) + 8 * (m >> 2);
#pragma unroll
        for (int g = 0; g < 2; ++g) {
            int idx = qb + g * 32 + row;
            if (idx < nq) wsd[idx] = rm[g * 16 + reg];
        }
    }
}

// Min over chunks + mean over queries. One block per (b, dir).
__global__ __launch_bounds__(256) void chamfer_reduce(const float* __restrict__ xyz1,
                                                      const float* __restrict__ xyz2,
                                                      const float* __restrict__ ws,
                                                      float* __restrict__ out,
                                                      int N, int M, int QCAP) {
    const int b = (int)blockIdx.x, dir = (int)blockIdx.y;
    const int B = gridDim.x;
    const float* __restrict__ P = dir ? xyz2 + (size_t)b * M * 3 : xyz1 + (size_t)b * N * 3;
    const int nq = dir ? M : N;
    const size_t cs = (size_t)2 * B * QCAP;                       // chunk stride
    const float* __restrict__ w0 = ws + ((size_t)dir * B + b) * QCAP;

    float s = 0.0f;
    for (int q = (int)threadIdx.x; q < nq; q += 256) {
        float v = w0[q];
#pragma unroll
        for (int c = 1; c < NSPLIT; ++c) v = fminf(v, w0[c * cs + q]);
        float x = P[3 * q], y = P[3 * q + 1], z = P[3 * q + 2];
        s += v + 0.5f * (x * x + y * y + z * z);
    }
#pragma unroll
    for (int off = 32; off > 0; off >>= 1) s += __shfl_down(s, off, 64);
    __shared__ float red[4];
    if ((threadIdx.x & 63) == 0) red[threadIdx.x >> 6] = s;
    __syncthreads();
    if (threadIdx.x == 0) {
        float t = (red[0] + red[1]) + (red[2] + red[3]);
        atomicAdd(out + b, t * (2.0f / (float)nq));   // dist = 2*(ph + min acc)
    }
}

extern "C" void kernel_launch(void* const* d_in, const int* in_sizes, int n_in,
                              void* d_out, int out_size, void* d_ws, size_t ws_size,
                              hipStream_t stream) {
    const float* xyz1 = (const float*)d_in[0];
    const float* xyz2 = (const float*)d_in[1];
    float* out = (float*)d_out;

    const int B = out_size;
    const int N = in_sizes[0] / (3 * B);
    const int M = in_sizes[1] / (3 * B);

    hipMemsetAsync(d_out, 0, (size_t)B * sizeof(float), stream);

    const int qmax    = N > M ? N : M;
    const int qblocks = (qmax + 255) / 256;
    const int QCAP    = qblocks * 256;
    // ws usage: NSPLIT * 2 * B * QCAP * 4 bytes (= 4 MiB at B=32, QCAP=4096)

    dim3 grid(qblocks * NSPLIT, B, 2);
    chamfer_mfma<<<grid, dim3(TPB), 0, stream>>>(xyz1, xyz2, (float*)d_ws, N, M, QCAP);
    chamfer_reduce<<<dim3(B, 2), dim3(256), 0, stream>>>(xyz1, xyz2, (float*)d_ws, out, N, M, QCAP);
}

// Round 5
// 117.296 us; speedup vs baseline: 13.5137x; 5.7690x over previous
//
#include <hip/hip_runtime.h>

typedef _Float16 half8 __attribute__((ext_vector_type(8)));
typedef float floatx16 __attribute__((ext_vector_type(16)));

#define TPB    256           // 4 waves
#define RPTS   256           // db points staged per round (= TPB: 1 pt/thread)
#define NTILE  (RPTS / 32)   // 8 tiles of 32 db points
#define SMH    (RPTS * 16)   // 4096 halfs = 8 KiB per buffer
#define NSPLIT 4             // md-split: blocks per (qblock, dir) pair

// 32x32x16 f16 MFMA formulation. Each wave owns 64 queries (2 A-frags x 32 rows);
// block = 256 queries x ONE md-chunk (md/NSPLIT db points). Partial per-query
// mins go to ws[chunk][dir][b][q] (4 MB); chamfer_reduce mins over chunks and
// mean-reduces. md-split rationale (R4): without it the grid holds 4 blocks/CU
// = 16 waves/CU and the kernel is latency-bound (28% occ, 19% MfmaUtil).
// R4 lesson: do NOT use __launch_bounds__(256,8) — the 64-reg budget gets split
// ~32 arch + 32 accum on gfx950's unified file, rm[32] spills, and the kernel
// runs at scratch bandwidth (2.3 GB writes, 618 us). Residency does NOT need
// the hint: the R2 body compiles to 64 VGPR under (256,4), which already
// hardware-allows 8 blocks/CU x 16 KiB LDS = 32 waves/CU; R4's grid supplies
// 16 blocks/CU. (256,4) + pinned-rolled sweep is the proven no-spill envelope.
// R3 lesson: do NOT unroll/group the sweep — 4 live floatx16 accs + rm[32]
// overflows even 128 VGPRs and spills rm to scratch (3.9 GB, 23x). The sweep
// below is pinned `#pragma unroll 1` (NTILE=8 is small enough to auto-unroll).
// R1 lesson: staging data in named scalars only — never arrays/pointers.
// K-slots (11 of 16 used):
//   B: (xh, xl, xh, yh, yl, yh, zh, zl | zh, hqh, hql, 0..)
//   A: (-xh,-xh,-xl,-yh,-yh,-yl,-zh,-zh | -zl, 1, 1, 0..)
// => acc = 0.5||q||^2 - p.q (split-f16, abs err ~5e-5);  dist = 2*(ph + min acc).
// A layout: row m = lane&31, k = (lane>>5)*8 + j.  B: col c = lane&31, same k.
// C/D: col = lane&31, row = (reg&3) + 8*(reg>>2) + 4*(lane>>5).

__device__ __forceinline__ void wr_point(_Float16* __restrict__ smb, int j,
                                         float x, float y, float z) {
    float hq = 0.5f * (x * x + y * y + z * z);
    _Float16 xh = (_Float16)x, yh = (_Float16)y, zh = (_Float16)z;
    _Float16 xl = (_Float16)(x - (float)xh);
    _Float16 yl = (_Float16)(y - (float)yh);
    _Float16 zl = (_Float16)(z - (float)zh);
    _Float16 qh = (_Float16)hq;
    _Float16 ql = (_Float16)(hq - (float)qh);
    const _Float16 hz = (_Float16)0.0f;
    int t = j >> 5, c = j & 31;
    half8 v0, v1;
    v0[0] = xh; v0[1] = xl; v0[2] = xh; v0[3] = yh;
    v0[4] = yl; v0[5] = yh; v0[6] = zh; v0[7] = zl;
    v1[0] = zh; v1[1] = qh; v1[2] = ql; v1[3] = hz;
    v1[4] = hz; v1[5] = hz; v1[6] = hz; v1[7] = hz;
    *(half8*)&smb[t * 512 + c * 8]       = v0;   // k-half 0
    *(half8*)&smb[t * 512 + 256 + c * 8] = v1;   // k-half 1
}

__global__ __launch_bounds__(TPB, 4) void chamfer_mfma(const float* __restrict__ xyz1,
                                                       const float* __restrict__ xyz2,
                                                       float* __restrict__ ws,
                                                       int N, int M, int QCAP) {
    const int b = blockIdx.y, dir = blockIdx.z;
    const int B = gridDim.y;
    const int qblock = (int)blockIdx.x / NSPLIT;
    const int chunk  = (int)blockIdx.x % NSPLIT;
    const float* __restrict__ P = dir ? xyz2 + (size_t)b * M * 3 : xyz1 + (size_t)b * N * 3;
    const float* __restrict__ Q = dir ? xyz1 + (size_t)b * N * 3 : xyz2 + (size_t)b * M * 3;
    const int nq = dir ? M : N;
    const int md = dir ? N : M;

    if (qblock * 256 >= nq) return;   // block-uniform, before any barrier

    // chunk range: CH rounds up so NSPLIT*CH covers md; clamp-pad handles excess
    const int CH   = ((md + NSPLIT * RPTS - 1) / (NSPLIT * RPTS)) * RPTS;
    const int base = chunk * CH;
    const int nrounds = CH / RPTS;    // >= 1

    __shared__ __align__(16) _Float16 smB[2][SMH];

    const int tid = (int)threadIdx.x;
    const int w   = tid >> 6;
    const int l   = tid & 63;
    const int m   = l & 31;      // A row / B col this lane serves
    const int h   = l >> 5;      // k-half: k = h*8 + j

    const _Float16 hz = (_Float16)0.0f, hone = (_Float16)1.0f;
    const int qb = qblock * 256 + w * 64;

    // ---- Build the wave's 2 A-fragments (held for the whole kernel) ----
    half8 afr[2];
#pragma unroll
    for (int g = 0; g < 2; ++g) {
        int idx = qb + g * 32 + m;
        int ci  = idx < nq ? idx : nq - 1;
        float x = P[3 * ci], y = P[3 * ci + 1], z = P[3 * ci + 2];
        _Float16 xh = (_Float16)x, yh = (_Float16)y, zh = (_Float16)z;
        _Float16 xl = (_Float16)(x - (float)xh);
        _Float16 yl = (_Float16)(y - (float)yh);
        _Float16 zl = (_Float16)(z - (float)zh);
        half8 a;
        if (h == 0) {
            a[0] = -xh; a[1] = -xh; a[2] = -xl; a[3] = -yh;
            a[4] = -yh; a[5] = -yl; a[6] = -zh; a[7] = -zh;
        } else {
            a[0] = -zl; a[1] = hone; a[2] = hone; a[3] = hz;
            a[4] = hz;  a[5] = hz;   a[6] = hz;  a[7] = hz;
        }
        afr[g] = a;
    }

    // ---- staging registers: named scalars ONLY (R1 lesson) ----
    float sx0, sy0, sz0;
#define LDPTS(rr) {                                                   \
        int g0 = base + (rr) * RPTS + tid;                            \
        g0 = g0 < md ? g0 : md - 1;  /* clamp-pad: dups never change a min */ \
        sx0 = Q[3 * g0]; sy0 = Q[3 * g0 + 1]; sz0 = Q[3 * g0 + 2];    \
    }
#define WRPTS(bb) { wr_point(&smB[bb][0], tid, sx0, sy0, sz0); }

    float rm[32];
#pragma unroll
    for (int i = 0; i < 32; ++i) rm[i] = 3.0e38f;

    const floatx16 czero = {0.0f, 0.0f, 0.0f, 0.0f, 0.0f, 0.0f, 0.0f, 0.0f,
                            0.0f, 0.0f, 0.0f, 0.0f, 0.0f, 0.0f, 0.0f, 0.0f};

    // ---- prologue: buf0 <- round 0; regs <- round 1 ----
    LDPTS(0);
    WRPTS(0);
    if (nrounds > 1) LDPTS(1);
    __syncthreads();

    const _Float16* bp0 = &smB[0][h * 256 + m * 8];
    const _Float16* bp1 = &smB[1][h * 256 + m * 8];

    int cur = 0;
    for (int r = 0; r < nrounds; ++r) {
        // write regs(r+1) -> other buffer; then issue loads for r+2
        if (r + 1 < nrounds) {
            WRPTS(cur ^ 1);
            if (r + 2 < nrounds) LDPTS(r + 2);
        }

        // ---- Sweep buf[cur]: rolled (R2 form — fits 64 VGPR, no scratch).
        // Pinned: NTILE=8 would otherwise auto-unroll and regroup -> R3 spill.
        const _Float16* bp = cur ? bp1 : bp0;
#pragma unroll 1
        for (int t = 0; t < NTILE; t += 2) {
            half8 b0 = *(const half8*)(bp + t * 512);
            half8 b1 = *(const half8*)(bp + t * 512 + 512);
            floatx16 d0a = __builtin_amdgcn_mfma_f32_32x32x16_f16(afr[0], b0, czero, 0, 0, 0);
            floatx16 d0b = __builtin_amdgcn_mfma_f32_32x32x16_f16(afr[0], b1, czero, 0, 0, 0);
#pragma unroll
            for (int i = 0; i < 16; ++i)
                rm[i] = fminf(fminf(rm[i], d0a[i]), d0b[i]);         // -> v_min3
            floatx16 d1a = __builtin_amdgcn_mfma_f32_32x32x16_f16(afr[1], b0, czero, 0, 0, 0);
            floatx16 d1b = __builtin_amdgcn_mfma_f32_32x32x16_f16(afr[1], b1, czero, 0, 0, 0);
#pragma unroll
            for (int i = 0; i < 16; ++i)
                rm[16 + i] = fminf(fminf(rm[16 + i], d1a[i]), d1b[i]);
        }

        if (r + 1 < nrounds) __syncthreads();   // uniform; last round skips
        cur ^= 1;
    }

    // ---- Col-min across the 32 lanes of each k-half (rows identical per half) ----
#pragma unroll
    for (int off = 1; off < 32; off <<= 1) {
#pragma unroll
        for (int i = 0; i < 32; ++i) rm[i] = fminf(rm[i], __shfl_xor(rm[i], off, 64));
    }

    // ---- Emit partial mins to ws[chunk][dir][b][q] ----
    float* __restrict__ wsd = ws + (((size_t)chunk * 2 + dir) * B + b) * QCAP;
    if (m < 16) {
        const int reg = (m & 3) + 4 * (m >> 2);
        const int row = 4 * h + (m & 3) + 8 * (m >> 2);
#pragma unroll
        for (int g = 0; g < 2; ++g) {
            int idx = qb + g * 32 + row;
            if (idx < nq) wsd[idx] = rm[g * 16 + reg];
        }
    }
}

// Min over chunks + mean over queries. One block per (b, dir).
__global__ __launch_bounds__(256) void chamfer_reduce(const float* __restrict__ xyz1,
                                                      const float* __restrict__ xyz2,
                                                      const float* __restrict__ ws,
                                                      float* __restrict__ out,
                                                      int N, int M, int QCAP) {
    const int b = (int)blockIdx.x, dir = (int)blockIdx.y;
    const int B = gridDim.x;
    const float* __restrict__ P = dir ? xyz2 + (size_t)b * M * 3 : xyz1 + (size_t)b * N * 3;
    const int nq = dir ? M : N;
    const size_t cs = (size_t)2 * B * QCAP;                       // chunk stride
    const float* __restrict__ w0 = ws + ((size_t)dir * B + b) * QCAP;

    float s = 0.0f;
    for (int q = (int)threadIdx.x; q < nq; q += 256) {
        float v = w0[q];
#pragma unroll
        for (int c = 1; c < NSPLIT; ++c) v = fminf(v, w0[c * cs + q]);
        float x = P[3 * q], y = P[3 * q + 1], z = P[3 * q + 2];
        s += v + 0.5f * (x * x + y * y + z * z);
    }
#pragma unroll
    for (int off = 32; off > 0; off >>= 1) s += __shfl_down(s, off, 64);
    __shared__ float red[4];
    if ((threadIdx.x & 63) == 0) red[threadIdx.x >> 6] = s;
    __syncthreads();
    if (threadIdx.x == 0) {
        float t = (red[0] + red[1]) + (red[2] + red[3]);
        atomicAdd(out + b, t * (2.0f / (float)nq));   // dist = 2*(ph + min acc)
    }
}

extern "C" void kernel_launch(void* const* d_in, const int* in_sizes, int n_in,
                              void* d_out, int out_size, void* d_ws, size_t ws_size,
                              hipStream_t stream) {
    const float* xyz1 = (const float*)d_in[0];
    const float* xyz2 = (const float*)d_in[1];
    float* out = (float*)d_out;

    const int B = out_size;
    const int N = in_sizes[0] / (3 * B);
    const int M = in_sizes[1] / (3 * B);

    hipMemsetAsync(d_out, 0, (size_t)B * sizeof(float), stream);

    const int qmax    = N > M ? N : M;
    const int qblocks = (qmax + 255) / 256;
    const int QCAP    = qblocks * 256;
    // ws usage: NSPLIT * 2 * B * QCAP * 4 bytes (= 4 MiB at B=32, QCAP=4096)

    dim3 grid(qblocks * NSPLIT, B, 2);
    chamfer_mfma<<<grid, dim3(TPB), 0, stream>>>(xyz1, xyz2, (float*)d_ws, N, M, QCAP);
    chamfer_reduce<<<dim3(B, 2), dim3(256), 0, stream>>>(xyz1, xyz2, (float*)d_ws, out, N, M, QCAP);
}

// Round 6
// 97.779 us; speedup vs baseline: 16.2109x; 1.1996x over previous
//
#include <hip/hip_runtime.h>

typedef _Float16 half8 __attribute__((ext_vector_type(8)));
typedef float floatx16 __attribute__((ext_vector_type(16)));

#define TPB    256           // 4 waves
#define RPTS   256           // db points staged per round (= TPB: 1 pt/thread)
#define NTILE  (RPTS / 32)   // 8 tiles of 32 db points
#define SMH    (RPTS * 16)   // 4096 halfs = 8 KiB per buffer
#define NSPLIT 4             // md-split: blocks per (qblock, dir) pair

// 32x32x16 f16 MFMA, SWAPPED-OPERAND form (R6): db points are the A operand
// (rows), queries are the B operand (cols). D col = lane&31 = query, so the
// min-over-db axis lies in the 16 accumulator REGS -> in-lane min3 tree
// (9 ops/MFMA), and the old 5-level x 32-reg lane butterfly (160 ds_swizzle +
// 160 min per wave; 61K DS-cycles/CU after md-split, the R5 bottleneck:
// VALUBusy 57%, DS pipe ~60%) collapses to 2 shfl_xor(32) + 2 min.
// A and B share the same lane->(index,k) mapping, so the LDS staging format
// and query-frag build are unchanged from R5 — only mfma operand order,
// fold, and emit differ. rm[32] -> rmq0/rmq1 also removes the register wall
// behind the R1/R3/R4 spills.
// Block = 256 queries x ONE md-chunk (md/NSPLIT db points); partial per-query
// mins -> ws[chunk][dir][b][q]; chamfer_reduce mins over chunks + mean.
// md-split rationale (R4/R5): without it only 16 waves/CU exist chip-wide.
// R4 lesson: no __launch_bounds__(256,8) — 64-reg budget split arch/accum,
//   spills, scratch-bandwidth kernel. Residency follows ACTUAL usage.
// R3 lesson: keep the sweep rolled (#pragma unroll 1), fold each MFMA result
//   immediately — never hold 4 floatx16 live.
// R1 lesson: staging data in named scalars only — never arrays/pointers.
// K-slots (11 of 16): A(db): (xh,xl,xh,yh,yl,yh,zh,zl | zh,hqh,hql,0..)
//                     B(qry): (-xh,-xh,-xl,-yh,-yh,-yl,-zh,-zh | -zl,1,1,0..)
// => acc = 0.5||q_db||^2 - p.q_db (split-f16); dist = 2*(0.5||p||^2 + min acc).
// A: row = lane&31, k = (lane>>5)*8+j.  B: col = lane&31, same k.
// C/D: col = lane&31 (query), row(db) = (reg&3)+8*(reg>>2)+4*(lane>>5)
//   -> regs cover 16 of 32 db rows; h-partner lane covers the other 16.

__device__ __forceinline__ void wr_point(_Float16* __restrict__ smb, int j,
                                         float x, float y, float z) {
    float hq = 0.5f * (x * x + y * y + z * z);
    _Float16 xh = (_Float16)x, yh = (_Float16)y, zh = (_Float16)z;
    _Float16 xl = (_Float16)(x - (float)xh);
    _Float16 yl = (_Float16)(y - (float)yh);
    _Float16 zl = (_Float16)(z - (float)zh);
    _Float16 qh = (_Float16)hq;
    _Float16 ql = (_Float16)(hq - (float)qh);
    const _Float16 hz = (_Float16)0.0f;
    int t = j >> 5, c = j & 31;
    half8 v0, v1;
    v0[0] = xh; v0[1] = xl; v0[2] = xh; v0[3] = yh;
    v0[4] = yl; v0[5] = yh; v0[6] = zh; v0[7] = zl;
    v1[0] = zh; v1[1] = qh; v1[2] = ql; v1[3] = hz;
    v1[4] = hz; v1[5] = hz; v1[6] = hz; v1[7] = hz;
    *(half8*)&smb[t * 512 + c * 8]       = v0;   // k-half 0
    *(half8*)&smb[t * 512 + 256 + c * 8] = v1;   // k-half 1
}

// min of 16 accumulator regs, min3-friendly grouping (8 v_min3 + 1 v_min)
__device__ __forceinline__ float fold16(floatx16 d) {
    float m0 = fminf(fminf(d[0],  d[1]),  d[2]);
    float m1 = fminf(fminf(d[3],  d[4]),  d[5]);
    float m2 = fminf(fminf(d[6],  d[7]),  d[8]);
    float m3 = fminf(fminf(d[9],  d[10]), d[11]);
    float m4 = fminf(fminf(d[12], d[13]), d[14]);
    float n0 = fminf(fminf(m0, m1), m2);
    float n1 = fminf(fminf(m3, m4), d[15]);
    return fminf(n0, n1);
}

__global__ __launch_bounds__(TPB, 4) void chamfer_mfma(const float* __restrict__ xyz1,
                                                       const float* __restrict__ xyz2,
                                                       float* __restrict__ ws,
                                                       int N, int M, int QCAP) {
    const int b = blockIdx.y, dir = blockIdx.z;
    const int B = gridDim.y;
    const int qblock = (int)blockIdx.x / NSPLIT;
    const int chunk  = (int)blockIdx.x % NSPLIT;
    const float* __restrict__ P = dir ? xyz2 + (size_t)b * M * 3 : xyz1 + (size_t)b * N * 3;
    const float* __restrict__ Q = dir ? xyz1 + (size_t)b * N * 3 : xyz2 + (size_t)b * M * 3;
    const int nq = dir ? M : N;
    const int md = dir ? N : M;

    if (qblock * 256 >= nq) return;   // block-uniform, before any barrier

    // chunk range: CH rounds up so NSPLIT*CH covers md; clamp-pad handles excess
    const int CH   = ((md + NSPLIT * RPTS - 1) / (NSPLIT * RPTS)) * RPTS;
    const int base = chunk * CH;
    const int nrounds = CH / RPTS;    // >= 1

    __shared__ __align__(16) _Float16 smB[2][SMH];

    const int tid = (int)threadIdx.x;
    const int w   = tid >> 6;
    const int l   = tid & 63;
    const int m   = l & 31;      // B col (query) this lane serves
    const int h   = l >> 5;      // k-half: k = h*8 + j

    const _Float16 hz = (_Float16)0.0f, hone = (_Float16)1.0f;
    const int qb = qblock * 256 + w * 64;

    // ---- Build the wave's 2 query B-fragments (held for the whole kernel) ----
    half8 qfr[2];
#pragma unroll
    for (int g = 0; g < 2; ++g) {
        int idx = qb + g * 32 + m;
        int ci  = idx < nq ? idx : nq - 1;
        float x = P[3 * ci], y = P[3 * ci + 1], z = P[3 * ci + 2];
        _Float16 xh = (_Float16)x, yh = (_Float16)y, zh = (_Float16)z;
        _Float16 xl = (_Float16)(x - (float)xh);
        _Float16 yl = (_Float16)(y - (float)yh);
        _Float16 zl = (_Float16)(z - (float)zh);
        half8 a;
        if (h == 0) {
            a[0] = -xh; a[1] = -xh; a[2] = -xl; a[3] = -yh;
            a[4] = -yh; a[5] = -yl; a[6] = -zh; a[7] = -zh;
        } else {
            a[0] = -zl; a[1] = hone; a[2] = hone; a[3] = hz;
            a[4] = hz;  a[5] = hz;   a[6] = hz;  a[7] = hz;
        }
        qfr[g] = a;
    }

    // ---- staging registers: named scalars ONLY (R1 lesson) ----
    float sx0, sy0, sz0;
#define LDPTS(rr) {                                                   \
        int g0 = base + (rr) * RPTS + tid;                            \
        g0 = g0 < md ? g0 : md - 1;  /* clamp-pad: dups never change a min */ \
        sx0 = Q[3 * g0]; sy0 = Q[3 * g0 + 1]; sz0 = Q[3 * g0 + 2];    \
    }
#define WRPTS(bb) { wr_point(&smB[bb][0], tid, sx0, sy0, sz0); }

    float rmq0 = 3.0e38f, rmq1 = 3.0e38f;   // running min for query cols g=0,1

    const floatx16 czero = {0.0f, 0.0f, 0.0f, 0.0f, 0.0f, 0.0f, 0.0f, 0.0f,
                            0.0f, 0.0f, 0.0f, 0.0f, 0.0f, 0.0f, 0.0f, 0.0f};

    // ---- prologue: buf0 <- round 0; regs <- round 1 ----
    LDPTS(0);
    WRPTS(0);
    if (nrounds > 1) LDPTS(1);
    __syncthreads();

    const _Float16* bp0 = &smB[0][h * 256 + m * 8];
    const _Float16* bp1 = &smB[1][h * 256 + m * 8];

    int cur = 0;
    for (int r = 0; r < nrounds; ++r) {
        // write regs(r+1) -> other buffer; then issue loads for r+2
        if (r + 1 < nrounds) {
            WRPTS(cur ^ 1);
            if (r + 2 < nrounds) LDPTS(r + 2);
        }

        // ---- Sweep buf[cur]: rolled, fold each MFMA result immediately ----
        const _Float16* bp = cur ? bp1 : bp0;
#pragma unroll 1
        for (int t = 0; t < NTILE; t += 2) {
            half8 a0 = *(const half8*)(bp + t * 512);
            half8 a1 = *(const half8*)(bp + t * 512 + 512);
            floatx16 d;
            d = __builtin_amdgcn_mfma_f32_32x32x16_f16(a0, qfr[0], czero, 0, 0, 0);
            rmq0 = fminf(rmq0, fold16(d));
            d = __builtin_amdgcn_mfma_f32_32x32x16_f16(a0, qfr[1], czero, 0, 0, 0);
            rmq1 = fminf(rmq1, fold16(d));
            d = __builtin_amdgcn_mfma_f32_32x32x16_f16(a1, qfr[0], czero, 0, 0, 0);
            rmq0 = fminf(rmq0, fold16(d));
            d = __builtin_amdgcn_mfma_f32_32x32x16_f16(a1, qfr[1], czero, 0, 0, 0);
            rmq1 = fminf(rmq1, fold16(d));
        }

        if (r + 1 < nrounds) __syncthreads();   // uniform; last round skips
        cur ^= 1;
    }

    // ---- Merge h-halves (regs covered 16 of 32 db rows; partner has rest) ----
    rmq0 = fminf(rmq0, __shfl_xor(rmq0, 32, 64));
    rmq1 = fminf(rmq1, __shfl_xor(rmq1, 32, 64));

    // ---- Emit: lane l owns query qb+l (h*32+m == l); coalesced write ----
    float* __restrict__ wsd = ws + (((size_t)chunk * 2 + dir) * B + b) * QCAP;
    const int idx = qb + l;
    const float val = h ? rmq1 : rmq0;
    if (idx < nq) wsd[idx] = val;
}

// Min over chunks + mean over queries. Blocks: (b, dir, qsplit of 4).
__global__ __launch_bounds__(256) void chamfer_reduce(const float* __restrict__ xyz1,
                                                      const float* __restrict__ xyz2,
                                                      const float* __restrict__ ws,
                                                      float* __restrict__ out,
                                                      int N, int M, int QCAP) {
    const int b = (int)blockIdx.x, dir = (int)blockIdx.y;
    const int B = gridDim.x;
    const float* __restrict__ P = dir ? xyz2 + (size_t)b * M * 3 : xyz1 + (size_t)b * N * 3;
    const int nq = dir ? M : N;
    const size_t cs = (size_t)2 * B * QCAP;                       // chunk stride
    const float* __restrict__ w0 = ws + ((size_t)dir * B + b) * QCAP;

    float s = 0.0f;
    for (int q = (int)threadIdx.x + (int)blockIdx.z * 256; q < nq; q += 256 * (int)gridDim.z) {
        float v = w0[q];
#pragma unroll
        for (int c = 1; c < NSPLIT; ++c) v = fminf(v, w0[c * cs + q]);
        float x = P[3 * q], y = P[3 * q + 1], z = P[3 * q + 2];
        s += v + 0.5f * (x * x + y * y + z * z);
    }
#pragma unroll
    for (int off = 32; off > 0; off >>= 1) s += __shfl_down(s, off, 64);
    __shared__ float red[4];
    if ((threadIdx.x & 63) == 0) red[threadIdx.x >> 6] = s;
    __syncthreads();
    if (threadIdx.x == 0) {
        float t = (red[0] + red[1]) + (red[2] + red[3]);
        atomicAdd(out + b, t * (2.0f / (float)nq));   // dist = 2*(ph + min acc)
    }
}

extern "C" void kernel_launch(void* const* d_in, const int* in_sizes, int n_in,
                              void* d_out, int out_size, void* d_ws, size_t ws_size,
                              hipStream_t stream) {
    const float* xyz1 = (const float*)d_in[0];
    const float* xyz2 = (const float*)d_in[1];
    float* out = (float*)d_out;

    const int B = out_size;
    const int N = in_sizes[0] / (3 * B);
    const int M = in_sizes[1] / (3 * B);

    hipMemsetAsync(d_out, 0, (size_t)B * sizeof(float), stream);

    const int qmax    = N > M ? N : M;
    const int qblocks = (qmax + 255) / 256;
    const int QCAP    = qblocks * 256;
    // ws usage: NSPLIT * 2 * B * QCAP * 4 bytes (= 4 MiB at B=32, QCAP=4096)

    dim3 grid(qblocks * NSPLIT, B, 2);
    chamfer_mfma<<<grid, dim3(TPB), 0, stream>>>(xyz1, xyz2, (float*)d_ws, N, M, QCAP);
    chamfer_reduce<<<dim3(B, 2, 4), dim3(256), 0, stream>>>(xyz1, xyz2, (float*)d_ws, out, N, M, QCAP);
}